// Round 1
// baseline (218.754 us; speedup 1.0000x reference)
//
#include <hip/hip_runtime.h>
#include <hip/hip_bf16.h>
#include <math.h>

// Problem shape (from reference setup_inputs): inp [B=16, S=4096, D=512] fp32,
// lengths [16] int32. Output [B, S, D+1] fp32: first D channels are a straight
// copy of inp; channel D is pe[b,s] = cos(s / max(len_b,1) * pi) if s < len_b
// else 0.
//
// Memory-bound: ~134 MB read + ~134.5 MB write. Strategy: one block per row
// (b*S + s), 256 threads; each thread copies 2 contiguous dwords (coalesced
// both sides — output row stride 513 floats forbids aligned float4 stores, so
// scalar dwords are the safe fully-coalesced width). Thread 0 computes the
// single positional value for the row.

#define PB 16
#define PS 4096
#define PD 512
#define PI_F 3.14159265358979323846f

__global__ __launch_bounds__(256) void sinpe_kernel(
    const float* __restrict__ inp,
    const int* __restrict__ lengths,
    float* __restrict__ out)
{
    const int row = blockIdx.x;            // 0 .. B*S-1
    const int s   = row & (PS - 1);        // position within sequence
    const int b   = row >> 12;             // row / 4096

    const float* __restrict__ in_row  = inp + (size_t)row * PD;
    float* __restrict__       out_row = out + (size_t)row * (PD + 1);

    const int t = threadIdx.x;             // 0..255

    // Copy D=512 floats: thread t handles elements t and t+256.
    out_row[t]       = in_row[t];
    out_row[t + 256] = in_row[t + 256];

    // Thread 0 writes the positional-embedding channel (element 512).
    if (t == 0) {
        const int len = lengths[b];
        float pe = 0.0f;
        if (s < len) {
            const float fl = fmaxf((float)len, 1.0f);
            pe = cosf(((float)s / fl) * PI_F);
        }
        out_row[PD] = pe;
    }
}

extern "C" void kernel_launch(void* const* d_in, const int* in_sizes, int n_in,
                              void* d_out, int out_size, void* d_ws, size_t ws_size,
                              hipStream_t stream)
{
    const float* inp     = (const float*)d_in[0];
    const int*   lengths = (const int*)d_in[1];
    float*       out     = (float*)d_out;

    const int n_rows = PB * PS;  // 65536
    sinpe_kernel<<<n_rows, 256, 0, stream>>>(inp, lengths, out);
}